// Round 15
// baseline (263.994 us; speedup 1.0000x reference)
//
#include <hip/hip_runtime.h>
#include <hip/hip_fp16.h>

// (B,H,S,D) = (4,8,2048,64), TEMP = 8.0
#define SS   2048
#define DD   64
#define NHH  8
#define NBB  4

typedef _Float16 half8_t   __attribute__((ext_vector_type(8)));
typedef _Float16 half16_t  __attribute__((ext_vector_type(16)));
typedef float    f32x16_t  __attribute__((ext_vector_type(16)));

#define LOG2E 1.4426950408889634f

// MFMA-fragment-contiguous layout for a [S][D] fp16 matrix:
// frag[bh][tile32][t(4)][g(2)][row32][8]  --  one wave load = 1KB contiguous.
static __device__ __forceinline__ size_t frag_idx(int bh, int kt, int t, int g, int col) {
    return ((((size_t)(bh * 64 + kt) * 4 + t) * 2 + g) * 32 + col) * 8;
}

// ---------------------------------------------------------------------------
// Kernel 1 (fused prep):
//  blocks [0,512):      q (scaled 0.125*log2e) + k fp32 -> fp16 fragments
//  blocks [512,1536):   v -> vT2 fragment layout
//  blocks [1536,5632):  Wt[b][k][q] = (1-pad_k)(1-sub)(dec), kt<=qt only
// ---------------------------------------------------------------------------
__global__ __launch_bounds__(256) void prep(const float* __restrict__ q,
                                            const float* __restrict__ k,
                                            const float* __restrict__ v,
                                            const float* __restrict__ pad,
                                            const float* __restrict__ sub,
                                            const float* __restrict__ dec,
                                            _Float16* __restrict__ qh2,
                                            _Float16* __restrict__ kh2,
                                            _Float16* __restrict__ vT2,
                                            _Float16* __restrict__ Wt) {
    __shared__ float smem[8768];            // 35.1KB, aliased per branch
    if (blockIdx.x < 512) {
        int bid = blockIdx.x;
        int wave = threadIdx.x >> 6, lane = threadIdx.x & 63;
        int col = lane & 31, g = lane >> 5;
        int bh = bid >> 4;
        int st = (bid & 15) * 4 + wave;          // 0..63 row tile
#pragma unroll
        for (int t = 0; t < 4; ++t) {
            const float* srcq = q + ((size_t)bh * SS + st * 32 + col) * DD + t * 16 + g * 8;
            const float* srck = k + ((size_t)bh * SS + st * 32 + col) * DD + t * 16 + g * 8;
            float va[8], vb[8];
            *(float4*)(va)     = *(const float4*)(srcq);
            *(float4*)(va + 4) = *(const float4*)(srcq + 4);
            *(float4*)(vb)     = *(const float4*)(srck);
            *(float4*)(vb + 4) = *(const float4*)(srck + 4);
            half8_t hq, hk;
#pragma unroll
            for (int e = 0; e < 8; ++e) {
                hq[e] = (_Float16)(va[e] * (0.125f * LOG2E));
                hk[e] = (_Float16)vb[e];
            }
            *(half8_t*)(qh2 + frag_idx(bh, st, t, g, col)) = hq;
            *(half8_t*)(kh2 + frag_idx(bh, st, t, g, col)) = hk;
        }
    } else if (blockIdx.x < 1536) {
        int bid = blockIdx.x - 512;
        float (*tile)[65] = (float(*)[65])smem;
        int bh = bid >> 5, kb = bid & 31;
        int k0 = kb * 64;
        int t = threadIdx.x;
#pragma unroll
        for (int it = 0; it < 16; ++it) {
            int idx = it * 256 + t;
            int r = idx >> 6, c = idx & 63;
            tile[r][c] = v[((size_t)bh * SS + k0 + r) * DD + c];
        }
        __syncthreads();
#pragma unroll
        for (int it = 0; it < 2; ++it) {
            int flat = it * 256 + t;            // 512 stores of 8 fp16
            int km8  = flat & 1;
            int d    = (flat >> 1) & 63;
            int k16l = flat >> 7;               // 0..3
            half8_t h;
#pragma unroll
            for (int e = 0; e < 8; ++e) h[e] = (_Float16)tile[k16l * 16 + km8 * 8 + e][d];
            *(half8_t*)(vT2 + (((size_t)bh * (SS / 16) + (k0 >> 4) + k16l) * DD + d) * 16 + km8 * 8) = h;
        }
    } else {
        // ---------------- make_wt ----------------
        int blk = blockIdx.x - 1536;
        int b  = blk >> 10;
        int qt = (blk >> 5) & 31;
        int kt = blk & 31;
        if (kt > qt) return;                    // never read by attn
        int q0 = qt * 64, k0 = kt * 64;
        const size_t bo = (size_t)b * SS * SS;

        float (*lsub)[68] = (float(*)[68])smem;
        float (*ldec)[68] = (float(*)[68])(smem + 64 * 68);
        float* lpad = smem + 2 * 64 * 68;
        int t = threadIdx.x;
        if (t < 64) lpad[t] = pad[bo + k0 + t];
#pragma unroll
        for (int it = 0; it < 4; ++it) {
            int idx = it * 256 + t;             // 1024 float4 per array
            int row = idx >> 4, c4 = idx & 15;
            *(float4*)(&lsub[row][c4 * 4]) = *(const float4*)(sub + bo + (size_t)(q0 + row) * SS + k0 + c4 * 4);
            *(float4*)(&ldec[row][c4 * 4]) = *(const float4*)(dec + bo + (size_t)(q0 + row) * SS + k0 + c4 * 4);
        }
        __syncthreads();
#pragma unroll
        for (int it = 0; it < 2; ++it) {
            int idx = it * 256 + t;             // 512 half8 stores
            int rk = idx >> 3, qc = idx & 7;
            int kg = k0 + rk;
            float fp = 1.0f - lpad[rk];
            half8_t w;
#pragma unroll
            for (int e = 0; e < 8; ++e) {
                int ql = qc * 8 + e;
                float val = (kg <= q0 + ql)
                          ? fp * (1.0f - lsub[ql][rk]) * ldec[ql][rk] : 0.0f;
                w[e] = (_Float16)val;
            }
            *(half8_t*)(Wt + ((size_t)b * SS + kg) * SS + q0 + qc * 8) = w;
        }
    }
}

// ---------------------------------------------------------------------------
// Kernel 2: FUSED attn. Phase 1: in-block lse over ALL 64 k-tiles (8/wave,
// online m/Z, LDS tree combine -> lsef[32]; no HBM round-trip). Phase 2:
// causal exp/store/PV loop (as round-12 attn_wt). part[] aliases the P tile
// (phase-separated by barrier); epilogue O-reduce aliases it too.
// ---------------------------------------------------------------------------
__global__ __launch_bounds__(512, 4) void attn_fused(
    const _Float16* __restrict__ qh2, const _Float16* __restrict__ kh2,
    const _Float16* __restrict__ vT2, const _Float16* __restrict__ Wt,
    float* __restrict__ outO, float* __restrict__ attnO) {
    __shared__ float shm[8][32 * 33];       // per-wave f32 P tile (33.8KB)
    __shared__ float lsef[32];              // final per-q lse (log2 domain)
    float* const redbase = &shm[0][0];      // epilogue + part alias
#define RED(i) (redbase + (i) * (64 * 33))

    int wave = threadIdx.x >> 6, lane = threadIdx.x & 63;
    int col = lane & 31, g = lane >> 5;

    // XCD-aware decode: heads of one (b,qb) cluster on one XCD.
    int blk = blockIdx.x;
    int xcd = blk & 7;
    int loc = blk >> 3;
    int h   = loc & 7;
    int t_  = loc >> 3;
    int b   = t_ & 3;
    int qhi = t_ >> 2;
    int qb  = qhi * 8 + xcd;
    int bh  = b * NHH + h;
    int q0  = qb * 32;

    half8_t aq[4];                      // Q fragments (B operand)
#pragma unroll
    for (int t = 0; t < 4; ++t)
        aq[t] = *(const half8_t*)(qh2 + frag_idx(bh, qb, t, g, col));

    const _Float16* Wtb = Wt + (size_t)b * SS * SS + q0 + col;   // lane = q
    // W prefetch for phase-2 first tile: issue BEFORE phase 1 (latency free)
    half16_t wv = {};
    if (wave <= qb) {
#pragma unroll
        for (int r = 0; r < 16; ++r) {
            int kl = (r & 3) + 8 * (r >> 2) + 4 * g;
            wv[r] = Wtb[(size_t)(wave * 32 + kl) * SS];
        }
    }

    // ---------------- phase 1: lse over all keys ----------------
    {
        half8_t ak[4];
#pragma unroll
        for (int t = 0; t < 4; ++t)
            ak[t] = *(const half8_t*)(kh2 + frag_idx(bh, wave, t, g, col));
        float m = -1e30f, Z = 0.f;
#pragma unroll
        for (int j = 0; j < 8; ++j) {
            f32x16_t acc{};
#pragma unroll
            for (int t = 0; t < 4; ++t)
                acc = __builtin_amdgcn_mfma_f32_32x32x16_f16(ak[t], aq[t], acc, 0, 0, 0);
            if (j < 7) {                        // self-overwriting prefetch
                int ktn = (j + 1) * 8 + wave;
#pragma unroll
                for (int t = 0; t < 4; ++t)
                    ak[t] = *(const half8_t*)(kh2 + frag_idx(bh, ktn, t, g, col));
            }
            float mloc = acc[0];
#pragma unroll
            for (int r = 1; r < 16; ++r) mloc = fmaxf(mloc, acc[r]);
            float mnew = fmaxf(m, mloc);
            float zadd = 0.f;
#pragma unroll
            for (int r = 0; r < 16; ++r) zadd += exp2f(acc[r] - mnew);
            Z = Z * exp2f(m - mnew) + zadd;
            m = mnew;
        }
        float mo = __shfl_xor(m, 32, 64);
        float Zo = __shfl_xor(Z, 32, 64);
        float mc = fmaxf(m, mo);
        float Zc = Z * exp2f(m - mc) + Zo * exp2f(mo - mc);
        float* part = redbase;                  // aliases shm (phase-safe)
        if (lane < 32) { part[wave * 64 + col * 2] = mc; part[wave * 64 + col * 2 + 1] = Zc; }
        __syncthreads();
        if (wave == 0 && lane < 32) {
            float M = part[col * 2], S = part[col * 2 + 1];
#pragma unroll
            for (int w = 1; w < 8; ++w) {
                float mw = part[w * 64 + col * 2], zw = part[w * 64 + col * 2 + 1];
                float Mn = fmaxf(M, mw);
                S = S * exp2f(M - Mn) + zw * exp2f(mw - Mn);
                M = Mn;
            }
            lsef[col] = M + __log2f(S);
        }
        __syncthreads();
    }
    float lv = lsef[col];                       // lane's q-row lse (log2)

    f32x16_t o0{}, o1{};
    float* pw = shm[wave];
    float* attnBase = attnO + ((size_t)bh * SS + q0) * SS;

    // K prefetch for phase-2 first tile (lines L2-warm from phase 1)
    half8_t kv[4];
    if (wave <= qb) {
#pragma unroll
        for (int t = 0; t < 4; ++t)
            kv[t] = *(const half8_t*)(kh2 + frag_idx(bh, wave, t, g, col));
    }

    // ---------------- phase 2: causal attn + PV ----------------
    for (int t8 = 0; t8 < 8; ++t8) {
        int kt = t8 * 8 + wave;             // interleaved k-tiles per wave
        int k0 = kt * 32;
        if (kt <= qb) {
            f32x16_t s{};
#pragma unroll
            for (int t = 0; t < 4; ++t)
                s = __builtin_amdgcn_mfma_f32_32x32x16_f16(kv[t], aq[t], s, 0, 0, 0);
            int ktn = kt + 8;
            if (ktn <= qb) {                // kv dead after MFMA issue: reload
#pragma unroll
                for (int t = 0; t < 4; ++t)
                    kv[t] = *(const half8_t*)(kh2 + frag_idx(bh, ktn, t, g, col));
            }
            // p = exp2(s - lse2) * w  -> f32 LDS tile [k][33q]
#pragma unroll
            for (int r = 0; r < 16; ++r) {
                int kl = (r & 3) + 8 * (r >> 2) + 4 * g;
                float p = exp2f(s[r] - lv) * (float)wv[r];
                pw[kl * 33 + col] = p;
            }
            // W prefetch for kt+8 (wv consumed)
            if (ktn <= qb) {
#pragma unroll
                for (int r = 0; r < 16; ++r) {
                    int kl = (r & 3) + 8 * (r >> 2) + 4 * g;
                    wv[r] = Wtb[(size_t)(ktn * 32 + kl) * SS];
                }
            }
            // attn store: read LDS transposed -> coalesced float4 rows
            {
                int c  = lane & 7;          // k-chunk (4 floats)
                int qr = lane >> 3;         // row base 0..7
#pragma unroll
                for (int i = 0; i < 4; ++i) {
                    int ql = qr + i * 8;
                    float4 v4;
                    v4.x = pw[(c * 4 + 0) * 33 + ql];
                    v4.y = pw[(c * 4 + 1) * 33 + ql];
                    v4.z = pw[(c * 4 + 2) * 33 + ql];
                    v4.w = pw[(c * 4 + 3) * 33 + ql];
                    *(float4*)(attnBase + (size_t)ql * SS + k0 + c * 4) = v4;
                }
            }
            // PV: fragments rebuilt fp16 from the f32 tile
#pragma unroll
            for (int kc = 0; kc < 2; ++kc) {
                half8_t pa;
#pragma unroll
                for (int j = 0; j < 8; ++j)
                    pa[j] = (_Float16)pw[(kc * 16 + g * 8 + j) * 33 + col];
                const _Float16* vb =
                    vT2 + (((size_t)bh * (SS / 16) + kt * 2 + kc) * DD + col) * 16 + g * 8;
                half8_t bv0 = *(const half8_t*)(vb);
                half8_t bv1 = *(const half8_t*)(vb + 32 * 16);
                o0 = __builtin_amdgcn_mfma_f32_32x32x16_f16(pa, bv0, o0, 0, 0, 0);
                o1 = __builtin_amdgcn_mfma_f32_32x32x16_f16(pa, bv1, o1, 0, 0, 0);
            }
        } else {
            // fully-causal-masked tile: attn is exactly zero
            float4 z4 = make_float4(0.f, 0.f, 0.f, 0.f);
#pragma unroll
            for (int it = 0; it < 4; ++it) {
                int flat = it * 64 + lane;
                int rr = flat >> 3, c4 = flat & 7;
                *(float4*)(attnBase + (size_t)rr * SS + k0 + c4 * 4) = z4;
            }
        }
    }

    // ---- O reduction: 8 partial tiles folded through 2 aliased buffers ----
    __syncthreads();                        // all waves done with P tiles
    if (wave == 4 || wave == 5) {
        float* rb = RED(wave - 4);
#pragma unroll
        for (int r = 0; r < 16; ++r) { rb[lane * 33 + r] = o0[r]; rb[lane * 33 + 16 + r] = o1[r]; }
    }
    __syncthreads();
    if (wave == 0 || wave == 1) {
        const float* rb = RED(wave);
#pragma unroll
        for (int r = 0; r < 16; ++r) { o0[r] += rb[lane * 33 + r]; o1[r] += rb[lane * 33 + 16 + r]; }
    }
    __syncthreads();
    if (wave == 6 || wave == 7) {
        float* rb = RED(wave - 6);
#pragma unroll
        for (int r = 0; r < 16; ++r) { rb[lane * 33 + r] = o0[r]; rb[lane * 33 + 16 + r] = o1[r]; }
    }
    __syncthreads();
    if (wave == 2 || wave == 3) {
        const float* rb = RED(wave - 2);
#pragma unroll
        for (int r = 0; r < 16; ++r) { o0[r] += rb[lane * 33 + r]; o1[r] += rb[lane * 33 + 16 + r]; }
    }
    __syncthreads();
    if (wave == 2 || wave == 3) {
        float* rb = RED(wave - 2);
#pragma unroll
        for (int r = 0; r < 16; ++r) { rb[lane * 33 + r] = o0[r]; rb[lane * 33 + 16 + r] = o1[r]; }
    }
    __syncthreads();
    if (wave == 0 || wave == 1) {
        const float* rb = RED(wave);
#pragma unroll
        for (int r = 0; r < 16; ++r) { o0[r] += rb[lane * 33 + r]; o1[r] += rb[lane * 33 + 16 + r]; }
    }
    __syncthreads();
    if (wave == 1) {
        float* rb = RED(0);
#pragma unroll
        for (int r = 0; r < 16; ++r) { rb[lane * 33 + r] = o0[r]; rb[lane * 33 + 16 + r] = o1[r]; }
    }
    __syncthreads();
    if (wave == 0) {
        const float* rb = RED(0);
        float* orow = outO + ((size_t)bh * SS + q0) * DD;
#pragma unroll
        for (int r = 0; r < 16; ++r) {
            int q_r = (r & 3) + 8 * (r >> 2) + 4 * g;
            orow[(size_t)q_r * DD + col]      = o0[r] + rb[lane * 33 + r];
            orow[(size_t)q_r * DD + 32 + col] = o1[r] + rb[lane * 33 + 16 + r];
        }
    }
#undef RED
}

// ---------------------------------------------------------------------------
extern "C" void kernel_launch(void* const* d_in, const int* in_sizes, int n_in,
                              void* d_out, int out_size, void* d_ws, size_t ws_size,
                              hipStream_t stream) {
    const float* q        = (const float*)d_in[0];
    const float* k        = (const float*)d_in[1];
    const float* v        = (const float*)d_in[2];
    const float* mask_pad = (const float*)d_in[3];
    const float* mask_sub = (const float*)d_in[4];
    /* d_in[5] mask_causal: deterministic triu(k=1) — handled structurally */
    const float* decay    = (const float*)d_in[6];

    float* out  = (float*)d_out;
    float* attn = out + (size_t)NBB * NHH * SS * DD;   // outputs concatenated

    const size_t NQK = (size_t)NBB * NHH * SS * DD;    // 4,194,304
    char* wsb = (char*)d_ws;
    _Float16* qh2 = (_Float16*)wsb;
    _Float16* kh2 = qh2 + NQK;
    _Float16* vT2 = kh2 + NQK;
    _Float16* Wc  = (_Float16*)(vT2 + NQK);            // 33.5 MB

    prep<<<5632, 256, 0, stream>>>(q, k, v, mask_pad, mask_sub, decay,
                                   qh2, kh2, vT2, Wc);
    attn_fused<<<NBB * NHH * 64, 512, 0, stream>>>(qh2, kh2, vT2, Wc, out, attn);
}

// Round 17
// 239.995 us; speedup vs baseline: 1.1000x; 1.1000x over previous
//
#include <hip/hip_runtime.h>
#include <hip/hip_fp16.h>

// (B,H,S,D) = (4,8,2048,64), TEMP = 8.0
#define SS   2048
#define DD   64
#define NHH  8
#define NBB  4

typedef _Float16 half8_t   __attribute__((ext_vector_type(8)));
typedef _Float16 half16_t  __attribute__((ext_vector_type(16)));
typedef float    f32x16_t  __attribute__((ext_vector_type(16)));
typedef float    f32x4_t   __attribute__((ext_vector_type(4)));   // clang vec: ok for nontemporal

#define LOG2E 1.4426950408889634f

// MFMA-fragment-contiguous layout for a [S][D] fp16 matrix:
// frag[bh][tile32][t(4)][g(2)][row32][8]  --  one wave load = 1KB contiguous.
static __device__ __forceinline__ size_t frag_idx(int bh, int kt, int t, int g, int col) {
    return ((((size_t)(bh * 64 + kt) * 4 + t) * 2 + g) * 32 + col) * 8;
}

// ---------------------------------------------------------------------------
// Kernel 1 (fused prep):
//  blocks [0,512):      q (scaled 0.125*log2e) + k fp32 -> fp16 fragments
//  blocks [512,1536):   v -> vT2 fragment layout
//  blocks [1536,5632):  Wt[b][k][q] = (1-pad_k)(1-sub)(dec), kt<=qt only
// ---------------------------------------------------------------------------
__global__ __launch_bounds__(256) void prep(const float* __restrict__ q,
                                            const float* __restrict__ k,
                                            const float* __restrict__ v,
                                            const float* __restrict__ pad,
                                            const float* __restrict__ sub,
                                            const float* __restrict__ dec,
                                            _Float16* __restrict__ qh2,
                                            _Float16* __restrict__ kh2,
                                            _Float16* __restrict__ vT2,
                                            _Float16* __restrict__ Wt) {
    __shared__ float smem[8768];            // 35.1KB, aliased per branch
    if (blockIdx.x < 512) {
        int bid = blockIdx.x;
        int wave = threadIdx.x >> 6, lane = threadIdx.x & 63;
        int col = lane & 31, g = lane >> 5;
        int bh = bid >> 4;
        int st = (bid & 15) * 4 + wave;          // 0..63 row tile
#pragma unroll
        for (int t = 0; t < 4; ++t) {
            const float* srcq = q + ((size_t)bh * SS + st * 32 + col) * DD + t * 16 + g * 8;
            const float* srck = k + ((size_t)bh * SS + st * 32 + col) * DD + t * 16 + g * 8;
            float va[8], vb[8];
            *(float4*)(va)     = *(const float4*)(srcq);
            *(float4*)(va + 4) = *(const float4*)(srcq + 4);
            *(float4*)(vb)     = *(const float4*)(srck);
            *(float4*)(vb + 4) = *(const float4*)(srck + 4);
            half8_t hq, hk;
#pragma unroll
            for (int e = 0; e < 8; ++e) {
                hq[e] = (_Float16)(va[e] * (0.125f * LOG2E));
                hk[e] = (_Float16)vb[e];
            }
            *(half8_t*)(qh2 + frag_idx(bh, st, t, g, col)) = hq;
            *(half8_t*)(kh2 + frag_idx(bh, st, t, g, col)) = hk;
        }
    } else if (blockIdx.x < 1536) {
        int bid = blockIdx.x - 512;
        float (*tile)[65] = (float(*)[65])smem;
        int bh = bid >> 5, kb = bid & 31;
        int k0 = kb * 64;
        int t = threadIdx.x;
#pragma unroll
        for (int it = 0; it < 16; ++it) {
            int idx = it * 256 + t;
            int r = idx >> 6, c = idx & 63;
            tile[r][c] = v[((size_t)bh * SS + k0 + r) * DD + c];
        }
        __syncthreads();
#pragma unroll
        for (int it = 0; it < 2; ++it) {
            int flat = it * 256 + t;            // 512 stores of 8 fp16
            int km8  = flat & 1;
            int d    = (flat >> 1) & 63;
            int k16l = flat >> 7;               // 0..3
            half8_t h;
#pragma unroll
            for (int e = 0; e < 8; ++e) h[e] = (_Float16)tile[k16l * 16 + km8 * 8 + e][d];
            *(half8_t*)(vT2 + (((size_t)bh * (SS / 16) + (k0 >> 4) + k16l) * DD + d) * 16 + km8 * 8) = h;
        }
    } else {
        // ---------------- make_wt ----------------
        int blk = blockIdx.x - 1536;
        int b  = blk >> 10;
        int qt = (blk >> 5) & 31;
        int kt = blk & 31;
        if (kt > qt) return;                    // never read by attn
        int q0 = qt * 64, k0 = kt * 64;
        const size_t bo = (size_t)b * SS * SS;

        float (*lsub)[68] = (float(*)[68])smem;
        float (*ldec)[68] = (float(*)[68])(smem + 64 * 68);
        float* lpad = smem + 2 * 64 * 68;
        int t = threadIdx.x;
        if (t < 64) lpad[t] = pad[bo + k0 + t];
#pragma unroll
        for (int it = 0; it < 4; ++it) {
            int idx = it * 256 + t;             // 1024 float4 per array
            int row = idx >> 4, c4 = idx & 15;
            *(float4*)(&lsub[row][c4 * 4]) = *(const float4*)(sub + bo + (size_t)(q0 + row) * SS + k0 + c4 * 4);
            *(float4*)(&ldec[row][c4 * 4]) = *(const float4*)(dec + bo + (size_t)(q0 + row) * SS + k0 + c4 * 4);
        }
        __syncthreads();
#pragma unroll
        for (int it = 0; it < 2; ++it) {
            int idx = it * 256 + t;             // 512 half8 stores
            int rk = idx >> 3, qc = idx & 7;
            int kg = k0 + rk;
            float fp = 1.0f - lpad[rk];
            half8_t w;
#pragma unroll
            for (int e = 0; e < 8; ++e) {
                int ql = qc * 8 + e;
                float val = (kg <= q0 + ql)
                          ? fp * (1.0f - lsub[ql][rk]) * ldec[ql][rk] : 0.0f;
                w[e] = (_Float16)val;
            }
            *(half8_t*)(Wt + ((size_t)b * SS + kg) * SS + q0 + qc * 8) = w;
        }
    }
}

// ---------------------------------------------------------------------------
// Kernel 2: FUSED attn. Phase 1: in-block lse over ALL 64 k-tiles. Phase 2:
// causal exp/store/PV loop. Attn-matrix stores (computed tiles AND zero
// tiles) are NONTEMPORAL (f32x4_t clang-vector form) -- the 537MB
// write-once stream no longer allocates in L2, so K/Q/Wt stay resident.
// ---------------------------------------------------------------------------
__global__ __launch_bounds__(512, 4) void attn_fused(
    const _Float16* __restrict__ qh2, const _Float16* __restrict__ kh2,
    const _Float16* __restrict__ vT2, const _Float16* __restrict__ Wt,
    float* __restrict__ outO, float* __restrict__ attnO) {
    __shared__ float shm[8][32 * 33];       // per-wave f32 P tile (33.8KB)
    __shared__ float lsef[32];              // final per-q lse (log2 domain)
    float* const redbase = &shm[0][0];      // epilogue + part alias
#define RED(i) (redbase + (i) * (64 * 33))

    int wave = threadIdx.x >> 6, lane = threadIdx.x & 63;
    int col = lane & 31, g = lane >> 5;

    // XCD-aware decode: heads of one (b,qb) cluster on one XCD.
    int blk = blockIdx.x;
    int xcd = blk & 7;
    int loc = blk >> 3;
    int h   = loc & 7;
    int t_  = loc >> 3;
    int b   = t_ & 3;
    int qhi = t_ >> 2;
    int qb  = qhi * 8 + xcd;
    int bh  = b * NHH + h;
    int q0  = qb * 32;

    half8_t aq[4];                      // Q fragments (B operand)
#pragma unroll
    for (int t = 0; t < 4; ++t)
        aq[t] = *(const half8_t*)(qh2 + frag_idx(bh, qb, t, g, col));

    const _Float16* Wtb = Wt + (size_t)b * SS * SS + q0 + col;   // lane = q
    // W prefetch for phase-2 first tile: issue BEFORE phase 1 (latency free)
    half16_t wv = {};
    if (wave <= qb) {
#pragma unroll
        for (int r = 0; r < 16; ++r) {
            int kl = (r & 3) + 8 * (r >> 2) + 4 * g;
            wv[r] = Wtb[(size_t)(wave * 32 + kl) * SS];
        }
    }

    // ---------------- phase 1: lse over all keys ----------------
    {
        half8_t ak[4];
#pragma unroll
        for (int t = 0; t < 4; ++t)
            ak[t] = *(const half8_t*)(kh2 + frag_idx(bh, wave, t, g, col));
        float m = -1e30f, Z = 0.f;
#pragma unroll
        for (int j = 0; j < 8; ++j) {
            f32x16_t acc{};
#pragma unroll
            for (int t = 0; t < 4; ++t)
                acc = __builtin_amdgcn_mfma_f32_32x32x16_f16(ak[t], aq[t], acc, 0, 0, 0);
            if (j < 7) {                        // self-overwriting prefetch
                int ktn = (j + 1) * 8 + wave;
#pragma unroll
                for (int t = 0; t < 4; ++t)
                    ak[t] = *(const half8_t*)(kh2 + frag_idx(bh, ktn, t, g, col));
            }
            float mloc = acc[0];
#pragma unroll
            for (int r = 1; r < 16; ++r) mloc = fmaxf(mloc, acc[r]);
            float mnew = fmaxf(m, mloc);
            float zadd = 0.f;
#pragma unroll
            for (int r = 0; r < 16; ++r) zadd += exp2f(acc[r] - mnew);
            Z = Z * exp2f(m - mnew) + zadd;
            m = mnew;
        }
        float mo = __shfl_xor(m, 32, 64);
        float Zo = __shfl_xor(Z, 32, 64);
        float mc = fmaxf(m, mo);
        float Zc = Z * exp2f(m - mc) + Zo * exp2f(mo - mc);
        float* part = redbase;                  // aliases shm (phase-safe)
        if (lane < 32) { part[wave * 64 + col * 2] = mc; part[wave * 64 + col * 2 + 1] = Zc; }
        __syncthreads();
        if (wave == 0 && lane < 32) {
            float M = part[col * 2], S = part[col * 2 + 1];
#pragma unroll
            for (int w = 1; w < 8; ++w) {
                float mw = part[w * 64 + col * 2], zw = part[w * 64 + col * 2 + 1];
                float Mn = fmaxf(M, mw);
                S = S * exp2f(M - Mn) + zw * exp2f(mw - Mn);
                M = Mn;
            }
            lsef[col] = M + __log2f(S);
        }
        __syncthreads();
    }
    float lv = lsef[col];                       // lane's q-row lse (log2)

    f32x16_t o0{}, o1{};
    float* pw = shm[wave];
    float* attnBase = attnO + ((size_t)bh * SS + q0) * SS;

    // K prefetch for phase-2 first tile (lines L2-warm from phase 1)
    half8_t kv[4];
    if (wave <= qb) {
#pragma unroll
        for (int t = 0; t < 4; ++t)
            kv[t] = *(const half8_t*)(kh2 + frag_idx(bh, wave, t, g, col));
    }

    // ---------------- phase 2: causal attn + PV ----------------
    for (int t8 = 0; t8 < 8; ++t8) {
        int kt = t8 * 8 + wave;             // interleaved k-tiles per wave
        int k0 = kt * 32;
        if (kt <= qb) {
            f32x16_t s{};
#pragma unroll
            for (int t = 0; t < 4; ++t)
                s = __builtin_amdgcn_mfma_f32_32x32x16_f16(kv[t], aq[t], s, 0, 0, 0);
            int ktn = kt + 8;
            if (ktn <= qb) {                // kv dead after MFMA issue: reload
#pragma unroll
                for (int t = 0; t < 4; ++t)
                    kv[t] = *(const half8_t*)(kh2 + frag_idx(bh, ktn, t, g, col));
            }
            // p = exp2(s - lse2) * w  -> f32 LDS tile [k][33q]
#pragma unroll
            for (int r = 0; r < 16; ++r) {
                int kl = (r & 3) + 8 * (r >> 2) + 4 * g;
                float p = exp2f(s[r] - lv) * (float)wv[r];
                pw[kl * 33 + col] = p;
            }
            // W prefetch for kt+8 (wv consumed)
            if (ktn <= qb) {
#pragma unroll
                for (int r = 0; r < 16; ++r) {
                    int kl = (r & 3) + 8 * (r >> 2) + 4 * g;
                    wv[r] = Wtb[(size_t)(ktn * 32 + kl) * SS];
                }
            }
            // attn store: read LDS transposed -> coalesced NONTEMPORAL stores
            {
                int c  = lane & 7;          // k-chunk (4 floats)
                int qr = lane >> 3;         // row base 0..7
#pragma unroll
                for (int i = 0; i < 4; ++i) {
                    int ql = qr + i * 8;
                    f32x4_t v4;
                    v4[0] = pw[(c * 4 + 0) * 33 + ql];
                    v4[1] = pw[(c * 4 + 1) * 33 + ql];
                    v4[2] = pw[(c * 4 + 2) * 33 + ql];
                    v4[3] = pw[(c * 4 + 3) * 33 + ql];
                    __builtin_nontemporal_store(v4,
                        (f32x4_t*)(attnBase + (size_t)ql * SS + k0 + c * 4));
                }
            }
            // PV: fragments rebuilt fp16 from the f32 tile
#pragma unroll
            for (int kc = 0; kc < 2; ++kc) {
                half8_t pa;
#pragma unroll
                for (int j = 0; j < 8; ++j)
                    pa[j] = (_Float16)pw[(kc * 16 + g * 8 + j) * 33 + col];
                const _Float16* vb =
                    vT2 + (((size_t)bh * (SS / 16) + kt * 2 + kc) * DD + col) * 16 + g * 8;
                half8_t bv0 = *(const half8_t*)(vb);
                half8_t bv1 = *(const half8_t*)(vb + 32 * 16);
                o0 = __builtin_amdgcn_mfma_f32_32x32x16_f16(pa, bv0, o0, 0, 0, 0);
                o1 = __builtin_amdgcn_mfma_f32_32x32x16_f16(pa, bv1, o1, 0, 0, 0);
            }
        } else {
            // fully-causal-masked tile: attn is exactly zero (nontemporal)
            f32x4_t z4 = {0.f, 0.f, 0.f, 0.f};
#pragma unroll
            for (int it = 0; it < 4; ++it) {
                int flat = it * 64 + lane;
                int rr = flat >> 3, c4 = flat & 7;
                __builtin_nontemporal_store(z4,
                    (f32x4_t*)(attnBase + (size_t)rr * SS + k0 + c4 * 4));
            }
        }
    }

    // ---- O reduction: 8 partial tiles folded through 2 aliased buffers ----
    __syncthreads();                        // all waves done with P tiles
    if (wave == 4 || wave == 5) {
        float* rb = RED(wave - 4);
#pragma unroll
        for (int r = 0; r < 16; ++r) { rb[lane * 33 + r] = o0[r]; rb[lane * 33 + 16 + r] = o1[r]; }
    }
    __syncthreads();
    if (wave == 0 || wave == 1) {
        const float* rb = RED(wave);
#pragma unroll
        for (int r = 0; r < 16; ++r) { o0[r] += rb[lane * 33 + r]; o1[r] += rb[lane * 33 + 16 + r]; }
    }
    __syncthreads();
    if (wave == 6 || wave == 7) {
        float* rb = RED(wave - 6);
#pragma unroll
        for (int r = 0; r < 16; ++r) { rb[lane * 33 + r] = o0[r]; rb[lane * 33 + 16 + r] = o1[r]; }
    }
    __syncthreads();
    if (wave == 2 || wave == 3) {
        const float* rb = RED(wave - 2);
#pragma unroll
        for (int r = 0; r < 16; ++r) { o0[r] += rb[lane * 33 + r]; o1[r] += rb[lane * 33 + 16 + r]; }
    }
    __syncthreads();
    if (wave == 2 || wave == 3) {
        float* rb = RED(wave - 2);
#pragma unroll
        for (int r = 0; r < 16; ++r) { rb[lane * 33 + r] = o0[r]; rb[lane * 33 + 16 + r] = o1[r]; }
    }
    __syncthreads();
    if (wave == 0 || wave == 1) {
        const float* rb = RED(wave);
#pragma unroll
        for (int r = 0; r < 16; ++r) { o0[r] += rb[lane * 33 + r]; o1[r] += rb[lane * 33 + 16 + r]; }
    }
    __syncthreads();
    if (wave == 1) {
        float* rb = RED(0);
#pragma unroll
        for (int r = 0; r < 16; ++r) { rb[lane * 33 + r] = o0[r]; rb[lane * 33 + 16 + r] = o1[r]; }
    }
    __syncthreads();
    if (wave == 0) {
        const float* rb = RED(0);
        float* orow = outO + ((size_t)bh * SS + q0) * DD;
#pragma unroll
        for (int r = 0; r < 16; ++r) {
            int q_r = (r & 3) + 8 * (r >> 2) + 4 * g;
            orow[(size_t)q_r * DD + col]      = o0[r] + rb[lane * 33 + r];
            orow[(size_t)q_r * DD + 32 + col] = o1[r] + rb[lane * 33 + 16 + r];
        }
    }
#undef RED
}

// ---------------------------------------------------------------------------
extern "C" void kernel_launch(void* const* d_in, const int* in_sizes, int n_in,
                              void* d_out, int out_size, void* d_ws, size_t ws_size,
                              hipStream_t stream) {
    const float* q        = (const float*)d_in[0];
    const float* k        = (const float*)d_in[1];
    const float* v        = (const float*)d_in[2];
    const float* mask_pad = (const float*)d_in[3];
    const float* mask_sub = (const float*)d_in[4];
    /* d_in[5] mask_causal: deterministic triu(k=1) — handled structurally */
    const float* decay    = (const float*)d_in[6];

    float* out  = (float*)d_out;
    float* attn = out + (size_t)NBB * NHH * SS * DD;   // outputs concatenated

    const size_t NQK = (size_t)NBB * NHH * SS * DD;    // 4,194,304
    char* wsb = (char*)d_ws;
    _Float16* qh2 = (_Float16*)wsb;
    _Float16* kh2 = qh2 + NQK;
    _Float16* vT2 = kh2 + NQK;
    _Float16* Wc  = (_Float16*)(vT2 + NQK);            // 33.5 MB

    prep<<<5632, 256, 0, stream>>>(q, k, v, mask_pad, mask_sub, decay,
                                   qh2, kh2, vT2, Wc);
    attn_fused<<<NBB * NHH * 64, 512, 0, stream>>>(qh2, kh2, vT2, Wc, out, attn);
}

// Round 18
// 166.490 us; speedup vs baseline: 1.5856x; 1.4415x over previous
//
#include <hip/hip_runtime.h>
#include <hip/hip_fp16.h>

// (B,H,S,D) = (4,8,2048,64), TEMP = 8.0
#define SS   2048
#define DD   64
#define NHH  8
#define NBB  4

typedef _Float16 half8_t   __attribute__((ext_vector_type(8)));
typedef _Float16 half16_t  __attribute__((ext_vector_type(16)));
typedef float    f32x16_t  __attribute__((ext_vector_type(16)));
typedef float    f32x4_t   __attribute__((ext_vector_type(4)));   // clang vec: ok for nontemporal

#define LOG2E 1.4426950408889634f

// MFMA-fragment-contiguous layout for a [S][D] fp16 matrix:
// frag[bh][tile32][t(4)][g(2)][row32][8]  --  one wave load = 1KB contiguous.
static __device__ __forceinline__ size_t frag_idx(int bh, int kt, int t, int g, int col) {
    return ((((size_t)(bh * 64 + kt) * 4 + t) * 2 + g) * 32 + col) * 8;
}

// ---------------------------------------------------------------------------
// Kernel 1 (fused prep):
//  blocks [0,512):      q (scaled 0.125*log2e) + k fp32 -> fp16 fragments
//  blocks [512,1536):   v -> vT2 fragment layout
//  blocks [1536,5632):  Wt[b][k][q] = (1-pad_k)(1-sub)(dec), kt<=qt only
// ---------------------------------------------------------------------------
__global__ __launch_bounds__(256) void prep(const float* __restrict__ q,
                                            const float* __restrict__ k,
                                            const float* __restrict__ v,
                                            const float* __restrict__ pad,
                                            const float* __restrict__ sub,
                                            const float* __restrict__ dec,
                                            _Float16* __restrict__ qh2,
                                            _Float16* __restrict__ kh2,
                                            _Float16* __restrict__ vT2,
                                            _Float16* __restrict__ Wt) {
    __shared__ float smem[8768];            // 35.1KB, aliased per branch
    if (blockIdx.x < 512) {
        int bid = blockIdx.x;
        int wave = threadIdx.x >> 6, lane = threadIdx.x & 63;
        int col = lane & 31, g = lane >> 5;
        int bh = bid >> 4;
        int st = (bid & 15) * 4 + wave;          // 0..63 row tile
#pragma unroll
        for (int t = 0; t < 4; ++t) {
            const float* srcq = q + ((size_t)bh * SS + st * 32 + col) * DD + t * 16 + g * 8;
            const float* srck = k + ((size_t)bh * SS + st * 32 + col) * DD + t * 16 + g * 8;
            float va[8], vb[8];
            *(float4*)(va)     = *(const float4*)(srcq);
            *(float4*)(va + 4) = *(const float4*)(srcq + 4);
            *(float4*)(vb)     = *(const float4*)(srck);
            *(float4*)(vb + 4) = *(const float4*)(srck + 4);
            half8_t hq, hk;
#pragma unroll
            for (int e = 0; e < 8; ++e) {
                hq[e] = (_Float16)(va[e] * (0.125f * LOG2E));
                hk[e] = (_Float16)vb[e];
            }
            *(half8_t*)(qh2 + frag_idx(bh, st, t, g, col)) = hq;
            *(half8_t*)(kh2 + frag_idx(bh, st, t, g, col)) = hk;
        }
    } else if (blockIdx.x < 1536) {
        int bid = blockIdx.x - 512;
        float (*tile)[65] = (float(*)[65])smem;
        int bh = bid >> 5, kb = bid & 31;
        int k0 = kb * 64;
        int t = threadIdx.x;
#pragma unroll
        for (int it = 0; it < 16; ++it) {
            int idx = it * 256 + t;
            int r = idx >> 6, c = idx & 63;
            tile[r][c] = v[((size_t)bh * SS + k0 + r) * DD + c];
        }
        __syncthreads();
#pragma unroll
        for (int it = 0; it < 2; ++it) {
            int flat = it * 256 + t;            // 512 stores of 8 fp16
            int km8  = flat & 1;
            int d    = (flat >> 1) & 63;
            int k16l = flat >> 7;               // 0..3
            half8_t h;
#pragma unroll
            for (int e = 0; e < 8; ++e) h[e] = (_Float16)tile[k16l * 16 + km8 * 8 + e][d];
            *(half8_t*)(vT2 + (((size_t)bh * (SS / 16) + (k0 >> 4) + k16l) * DD + d) * 16 + km8 * 8) = h;
        }
    } else {
        // ---------------- make_wt ----------------
        int blk = blockIdx.x - 1536;
        int b  = blk >> 10;
        int qt = (blk >> 5) & 31;
        int kt = blk & 31;
        if (kt > qt) return;                    // never read by attn
        int q0 = qt * 64, k0 = kt * 64;
        const size_t bo = (size_t)b * SS * SS;

        float (*lsub)[68] = (float(*)[68])smem;
        float (*ldec)[68] = (float(*)[68])(smem + 64 * 68);
        float* lpad = smem + 2 * 64 * 68;
        int t = threadIdx.x;
        if (t < 64) lpad[t] = pad[bo + k0 + t];
#pragma unroll
        for (int it = 0; it < 4; ++it) {
            int idx = it * 256 + t;             // 1024 float4 per array
            int row = idx >> 4, c4 = idx & 15;
            *(float4*)(&lsub[row][c4 * 4]) = *(const float4*)(sub + bo + (size_t)(q0 + row) * SS + k0 + c4 * 4);
            *(float4*)(&ldec[row][c4 * 4]) = *(const float4*)(dec + bo + (size_t)(q0 + row) * SS + k0 + c4 * 4);
        }
        __syncthreads();
#pragma unroll
        for (int it = 0; it < 2; ++it) {
            int idx = it * 256 + t;             // 512 half8 stores
            int rk = idx >> 3, qc = idx & 7;
            int kg = k0 + rk;
            float fp = 1.0f - lpad[rk];
            half8_t w;
#pragma unroll
            for (int e = 0; e < 8; ++e) {
                int ql = qc * 8 + e;
                float val = (kg <= q0 + ql)
                          ? fp * (1.0f - lsub[ql][rk]) * ldec[ql][rk] : 0.0f;
                w[e] = (_Float16)val;
            }
            *(half8_t*)(Wt + ((size_t)b * SS + kg) * SS + q0 + qc * 8) = w;
        }
    }
}

// ---------------------------------------------------------------------------
// Kernel 2: FUSED attn. Phase 1: in-block lse over ALL 64 k-tiles. Phase 2:
// causal exp/store/PV with NONTEMPORAL attn stores. NEW XCD decode: qhi is
// the fastest-varying per-XCD index, so the 8 q-tile blocks of one bh are
// CONSECUTIVE on their XCD -> K[bh] (512KB) is read from HBM ~once per XCD
// and L2-hits for the other 7 blocks (was: 32-loc separation, evicted).
// ---------------------------------------------------------------------------
__global__ __launch_bounds__(512, 4) void attn_fused(
    const _Float16* __restrict__ qh2, const _Float16* __restrict__ kh2,
    const _Float16* __restrict__ vT2, const _Float16* __restrict__ Wt,
    float* __restrict__ outO, float* __restrict__ attnO) {
    __shared__ float shm[8][32 * 33];       // per-wave f32 P tile (33.8KB)
    __shared__ float lsef[32];              // final per-q lse (log2 domain)
    float* const redbase = &shm[0][0];      // epilogue + part alias
#define RED(i) (redbase + (i) * (64 * 33))

    int wave = threadIdx.x >> 6, lane = threadIdx.x & 63;
    int col = lane & 31, g = lane >> 5;

    // XCD decode: qhi fastest (same-bh blocks consecutive -> K L2 reuse),
    // then h, then b. qb residue == xcd keeps triangular work balanced.
    int blk = blockIdx.x;
    int xcd = blk & 7;
    int loc = blk >> 3;                 // 0..255 per-XCD sequence
    int qhi = loc & 7;
    int rest = loc >> 3;                // 0..31
    int h   = rest & 7;
    int b   = rest >> 3;
    int qb  = qhi * 8 + xcd;
    int bh  = b * NHH + h;
    int q0  = qb * 32;

    half8_t aq[4];                      // Q fragments (B operand)
#pragma unroll
    for (int t = 0; t < 4; ++t)
        aq[t] = *(const half8_t*)(qh2 + frag_idx(bh, qb, t, g, col));

    const _Float16* Wtb = Wt + (size_t)b * SS * SS + q0 + col;   // lane = q
    // W prefetch for phase-2 first tile: issue BEFORE phase 1 (latency free)
    half16_t wv = {};
    if (wave <= qb) {
#pragma unroll
        for (int r = 0; r < 16; ++r) {
            int kl = (r & 3) + 8 * (r >> 2) + 4 * g;
            wv[r] = Wtb[(size_t)(wave * 32 + kl) * SS];
        }
    }

    // ---------------- phase 1: lse over all keys ----------------
    {
        half8_t ak[4];
#pragma unroll
        for (int t = 0; t < 4; ++t)
            ak[t] = *(const half8_t*)(kh2 + frag_idx(bh, wave, t, g, col));
        float m = -1e30f, Z = 0.f;
#pragma unroll
        for (int j = 0; j < 8; ++j) {
            f32x16_t acc{};
#pragma unroll
            for (int t = 0; t < 4; ++t)
                acc = __builtin_amdgcn_mfma_f32_32x32x16_f16(ak[t], aq[t], acc, 0, 0, 0);
            if (j < 7) {                        // self-overwriting prefetch
                int ktn = (j + 1) * 8 + wave;
#pragma unroll
                for (int t = 0; t < 4; ++t)
                    ak[t] = *(const half8_t*)(kh2 + frag_idx(bh, ktn, t, g, col));
            }
            float mloc = acc[0];
#pragma unroll
            for (int r = 1; r < 16; ++r) mloc = fmaxf(mloc, acc[r]);
            float mnew = fmaxf(m, mloc);
            float zadd = 0.f;
#pragma unroll
            for (int r = 0; r < 16; ++r) zadd += exp2f(acc[r] - mnew);
            Z = Z * exp2f(m - mnew) + zadd;
            m = mnew;
        }
        float mo = __shfl_xor(m, 32, 64);
        float Zo = __shfl_xor(Z, 32, 64);
        float mc = fmaxf(m, mo);
        float Zc = Z * exp2f(m - mc) + Zo * exp2f(mo - mc);
        float* part = redbase;                  // aliases shm (phase-safe)
        if (lane < 32) { part[wave * 64 + col * 2] = mc; part[wave * 64 + col * 2 + 1] = Zc; }
        __syncthreads();
        if (wave == 0 && lane < 32) {
            float M = part[col * 2], S = part[col * 2 + 1];
#pragma unroll
            for (int w = 1; w < 8; ++w) {
                float mw = part[w * 64 + col * 2], zw = part[w * 64 + col * 2 + 1];
                float Mn = fmaxf(M, mw);
                S = S * exp2f(M - Mn) + zw * exp2f(mw - Mn);
                M = Mn;
            }
            lsef[col] = M + __log2f(S);
        }
        __syncthreads();
    }
    float lv = lsef[col];                       // lane's q-row lse (log2)

    f32x16_t o0{}, o1{};
    float* pw = shm[wave];
    float* attnBase = attnO + ((size_t)bh * SS + q0) * SS;

    // K prefetch for phase-2 first tile (lines L2-warm from phase 1)
    half8_t kv[4];
    if (wave <= qb) {
#pragma unroll
        for (int t = 0; t < 4; ++t)
            kv[t] = *(const half8_t*)(kh2 + frag_idx(bh, wave, t, g, col));
    }

    // ---------------- phase 2: causal attn + PV ----------------
    for (int t8 = 0; t8 < 8; ++t8) {
        int kt = t8 * 8 + wave;             // interleaved k-tiles per wave
        int k0 = kt * 32;
        if (kt <= qb) {
            f32x16_t s{};
#pragma unroll
            for (int t = 0; t < 4; ++t)
                s = __builtin_amdgcn_mfma_f32_32x32x16_f16(kv[t], aq[t], s, 0, 0, 0);
            int ktn = kt + 8;
            if (ktn <= qb) {                // kv dead after MFMA issue: reload
#pragma unroll
                for (int t = 0; t < 4; ++t)
                    kv[t] = *(const half8_t*)(kh2 + frag_idx(bh, ktn, t, g, col));
            }
            // p = exp2(s - lse2) * w  -> f32 LDS tile [k][33q]
#pragma unroll
            for (int r = 0; r < 16; ++r) {
                int kl = (r & 3) + 8 * (r >> 2) + 4 * g;
                float p = exp2f(s[r] - lv) * (float)wv[r];
                pw[kl * 33 + col] = p;
            }
            // W prefetch for kt+8 (wv consumed)
            if (ktn <= qb) {
#pragma unroll
                for (int r = 0; r < 16; ++r) {
                    int kl = (r & 3) + 8 * (r >> 2) + 4 * g;
                    wv[r] = Wtb[(size_t)(ktn * 32 + kl) * SS];
                }
            }
            // attn store: read LDS transposed -> coalesced NONTEMPORAL stores
            {
                int c  = lane & 7;          // k-chunk (4 floats)
                int qr = lane >> 3;         // row base 0..7
#pragma unroll
                for (int i = 0; i < 4; ++i) {
                    int ql = qr + i * 8;
                    f32x4_t v4;
                    v4[0] = pw[(c * 4 + 0) * 33 + ql];
                    v4[1] = pw[(c * 4 + 1) * 33 + ql];
                    v4[2] = pw[(c * 4 + 2) * 33 + ql];
                    v4[3] = pw[(c * 4 + 3) * 33 + ql];
                    __builtin_nontemporal_store(v4,
                        (f32x4_t*)(attnBase + (size_t)ql * SS + k0 + c * 4));
                }
            }
            // PV: fragments rebuilt fp16 from the f32 tile
#pragma unroll
            for (int kc = 0; kc < 2; ++kc) {
                half8_t pa;
#pragma unroll
                for (int j = 0; j < 8; ++j)
                    pa[j] = (_Float16)pw[(kc * 16 + g * 8 + j) * 33 + col];
                const _Float16* vb =
                    vT2 + (((size_t)bh * (SS / 16) + kt * 2 + kc) * DD + col) * 16 + g * 8;
                half8_t bv0 = *(const half8_t*)(vb);
                half8_t bv1 = *(const half8_t*)(vb + 32 * 16);
                o0 = __builtin_amdgcn_mfma_f32_32x32x16_f16(pa, bv0, o0, 0, 0, 0);
                o1 = __builtin_amdgcn_mfma_f32_32x32x16_f16(pa, bv1, o1, 0, 0, 0);
            }
        } else {
            // fully-causal-masked tile: attn is exactly zero (nontemporal)
            f32x4_t z4 = {0.f, 0.f, 0.f, 0.f};
#pragma unroll
            for (int it = 0; it < 4; ++it) {
                int flat = it * 64 + lane;
                int rr = flat >> 3, c4 = flat & 7;
                __builtin_nontemporal_store(z4,
                    (f32x4_t*)(attnBase + (size_t)rr * SS + k0 + c4 * 4));
            }
        }
    }

    // ---- O reduction: 8 partial tiles folded through 2 aliased buffers ----
    __syncthreads();                        // all waves done with P tiles
    if (wave == 4 || wave == 5) {
        float* rb = RED(wave - 4);
#pragma unroll
        for (int r = 0; r < 16; ++r) { rb[lane * 33 + r] = o0[r]; rb[lane * 33 + 16 + r] = o1[r]; }
    }
    __syncthreads();
    if (wave == 0 || wave == 1) {
        const float* rb = RED(wave);
#pragma unroll
        for (int r = 0; r < 16; ++r) { o0[r] += rb[lane * 33 + r]; o1[r] += rb[lane * 33 + 16 + r]; }
    }
    __syncthreads();
    if (wave == 6 || wave == 7) {
        float* rb = RED(wave - 6);
#pragma unroll
        for (int r = 0; r < 16; ++r) { rb[lane * 33 + r] = o0[r]; rb[lane * 33 + 16 + r] = o1[r]; }
    }
    __syncthreads();
    if (wave == 2 || wave == 3) {
        const float* rb = RED(wave - 2);
#pragma unroll
        for (int r = 0; r < 16; ++r) { o0[r] += rb[lane * 33 + r]; o1[r] += rb[lane * 33 + 16 + r]; }
    }
    __syncthreads();
    if (wave == 2 || wave == 3) {
        float* rb = RED(wave - 2);
#pragma unroll
        for (int r = 0; r < 16; ++r) { rb[lane * 33 + r] = o0[r]; rb[lane * 33 + 16 + r] = o1[r]; }
    }
    __syncthreads();
    if (wave == 0 || wave == 1) {
        const float* rb = RED(wave);
#pragma unroll
        for (int r = 0; r < 16; ++r) { o0[r] += rb[lane * 33 + r]; o1[r] += rb[lane * 33 + 16 + r]; }
    }
    __syncthreads();
    if (wave == 1) {
        float* rb = RED(0);
#pragma unroll
        for (int r = 0; r < 16; ++r) { rb[lane * 33 + r] = o0[r]; rb[lane * 33 + 16 + r] = o1[r]; }
    }
    __syncthreads();
    if (wave == 0) {
        const float* rb = RED(0);
        float* orow = outO + ((size_t)bh * SS + q0) * DD;
#pragma unroll
        for (int r = 0; r < 16; ++r) {
            int q_r = (r & 3) + 8 * (r >> 2) + 4 * g;
            orow[(size_t)q_r * DD + col]      = o0[r] + rb[lane * 33 + r];
            orow[(size_t)q_r * DD + 32 + col] = o1[r] + rb[lane * 33 + 16 + r];
        }
    }
#undef RED
}

// ---------------------------------------------------------------------------
extern "C" void kernel_launch(void* const* d_in, const int* in_sizes, int n_in,
                              void* d_out, int out_size, void* d_ws, size_t ws_size,
                              hipStream_t stream) {
    const float* q        = (const float*)d_in[0];
    const float* k        = (const float*)d_in[1];
    const float* v        = (const float*)d_in[2];
    const float* mask_pad = (const float*)d_in[3];
    const float* mask_sub = (const float*)d_in[4];
    /* d_in[5] mask_causal: deterministic triu(k=1) — handled structurally */
    const float* decay    = (const float*)d_in[6];

    float* out  = (float*)d_out;
    float* attn = out + (size_t)NBB * NHH * SS * DD;   // outputs concatenated

    const size_t NQK = (size_t)NBB * NHH * SS * DD;    // 4,194,304
    char* wsb = (char*)d_ws;
    _Float16* qh2 = (_Float16*)wsb;
    _Float16* kh2 = qh2 + NQK;
    _Float16* vT2 = kh2 + NQK;
    _Float16* Wc  = (_Float16*)(vT2 + NQK);            // 33.5 MB

    prep<<<5632, 256, 0, stream>>>(q, k, v, mask_pad, mask_sub, decay,
                                   qh2, kh2, vT2, Wc);
    attn_fused<<<NBB * NHH * 64, 512, 0, stream>>>(qh2, kh2, vT2, Wc, out, attn);
}